// Round 1
// baseline (973.760 us; speedup 1.0000x reference)
//
#include <hip/hip_runtime.h>
#include <hip/hip_bf16.h>

// Problem constants (match reference setup_inputs)
constexpr int B_   = 2048;
constexpr int L_   = 200;
constexpr int C_   = 100;
constexpr int DID_ = 64;
constexpr int DTXT_= 128;
constexpr int DCTX_= 128;
constexpr int KWIN = 5;
constexpr int V_   = 2000;
constexpr int DIN_ = DID_ + DTXT_;   // 192
constexpr int HID_ = 128;
constexpr int TB   = 4;              // batches per k1 block

// ---------------------------------------------------------------------------
// ws layout (floats): u_t B*128 | u_i B*128 | alp B*3 | WihT 192*384 |
// WhhT 128*384 | Wt1uT 256*128 | Wt1sT 128*128 | Wi1uT 192*128 |
// Wi1sT 64*128 | Wa1T 128*64
// k-major transposes: WT[k*rows + row] = W[row*K + k]

__global__ __launch_bounds__(256) void k0_transpose(
    const float* __restrict__ W_ih, const float* __restrict__ W_hh,
    const float* __restrict__ Wt1,  const float* __restrict__ Wi1,
    const float* __restrict__ Wa1,
    float* __restrict__ WihT,  float* __restrict__ WhhT,
    float* __restrict__ Wt1uT, float* __restrict__ Wt1sT,
    float* __restrict__ Wi1uT, float* __restrict__ Wi1sT,
    float* __restrict__ Wa1T)
{
  int idx = blockIdx.x*256 + threadIdx.x;
  int stride = gridDim.x*256;
  for (int i = idx; i < 192*384; i += stride) {
    int k = i/384, r = i%384; WihT[i] = W_ih[r*192 + k];
  }
  for (int i = idx; i < 128*384; i += stride) {
    int k = i/384, r = i%384; WhhT[i] = W_hh[r*128 + k];
  }
  for (int i = idx; i < 256*128; i += stride) {
    int k = i/128, j = i%128;
    Wt1uT[i] = (k < 128) ? Wt1[j*384 + k] : Wt1[j*384 + 256 + (k-128)];
  }
  for (int i = idx; i < 128*128; i += stride) {
    int k = i/128, j = i%128; Wt1sT[i] = Wt1[j*384 + 128 + k];
  }
  for (int i = idx; i < 192*128; i += stride) {
    int k = i/128, j = i%128;
    Wi1uT[i] = (k < 64) ? Wi1[j*256 + k] : Wi1[j*256 + 128 + (k-64)];
  }
  for (int i = idx; i < 64*128; i += stride) {
    int k = i/128, j = i%128; Wi1sT[i] = Wi1[j*256 + 64 + k];
  }
  for (int i = idx; i < 128*64; i += stride) {
    int k = i/64, u = i%64; Wa1T[i] = Wa1[u*128 + k];
  }
}

__device__ __forceinline__ float sigm(float x) { return 1.f/(1.f + __expf(-x)); }

// ---------------------------------------------------------------------------
// K1: GRU + heads, weight reads amortized over TB batches and (for W_ih) all
// 5 timesteps. Thread tid<192 owns output-row pair r0=2tid of the 384 rows.
// Weights streamed k-major (coalesced, once per block per use); activations
// broadcast from LDS (wave-uniform b128 reads, conflict-free).
// ---------------------------------------------------------------------------
__global__ __launch_bounds__(256) void k1_gru(
    const int*   __restrict__ lengths,
    const float* __restrict__ seq_id,
    const float* __restrict__ seq_text,
    const float* __restrict__ WihT, const float* __restrict__ WhhT,
    const float* __restrict__ b_ih, const float* __restrict__ b_hh,
    const float* __restrict__ Wt1uT, const float* __restrict__ bt1,
    const float* __restrict__ Wi1uT, const float* __restrict__ bi1,
    const float* __restrict__ Wa1T,  const float* __restrict__ ba1,
    const float* __restrict__ Wa2,   const float* __restrict__ ba2,
    float* __restrict__ u_t, float* __restrict__ u_i,
    float* __restrict__ alp)
{
  __shared__ float xk[TB][KWIN][DIN_];       // 15360 B
  __shared__ float G[KWIN*TB*384];           // 30720 B  input projections
  __shared__ float Hacc[TB][384];            //  6144 B  per-t hidden proj
  __shared__ float hbuf[2][TB][DCTX_];       //  4096 B
  __shared__ float ltext[TB][DTXT_];         //  2048 B
  __shared__ float lid[TB][DID_];            //  1024 B
  __shared__ float a1s[TB][64];              //  1024 B
  __shared__ int   s_start[TB], s_last[TB];

  const int tid = threadIdx.x;
  const int b0  = blockIdx.x * TB;

  if (tid < TB) {
    int len = lengths[b0 + tid];
    s_start[tid] = len - KWIN;
    s_last[tid]  = len - 1;
  }
  __syncthreads();

  // ---- stage inputs (coalesced float4 within rows)
  for (int i = tid; i < TB*KWIN*(DID_/4); i += 256) {
    int bb = i/(KWIN*16), r = i%(KWIN*16), t = r/16, q = r%16;
    ((float4*)&xk[bb][t][0])[q] =
      ((const float4*)(seq_id + ((size_t)(b0+bb)*L_ + s_start[bb]+t)*DID_))[q];
  }
  for (int i = tid; i < TB*KWIN*(DTXT_/4); i += 256) {
    int bb = i/(KWIN*32), r = i%(KWIN*32), t = r/32, q = r%32;
    ((float4*)&xk[bb][t][DID_])[q] =
      ((const float4*)(seq_text + ((size_t)(b0+bb)*L_ + s_start[bb]+t)*DTXT_))[q];
  }
  for (int i = tid; i < TB*(DTXT_/4); i += 256) {
    int bb = i/32, q = i%32;
    ((float4*)ltext[bb])[q] =
      ((const float4*)(seq_text + ((size_t)(b0+bb)*L_ + s_last[bb])*DTXT_))[q];
  }
  for (int i = tid; i < TB*(DID_/4); i += 256) {
    int bb = i/16, q = i%16;
    ((float4*)lid[bb])[q] =
      ((const float4*)(seq_id + ((size_t)(b0+bb)*L_ + s_last[bb])*DID_))[q];
  }
  for (int i = tid; i < TB*DCTX_; i += 256) ((float*)hbuf[0])[i] = 0.f;
  __syncthreads();

  // ---- Phase A: input projections for all 5 steps, WihT read ONCE per block
  if (tid < 192) {
    const int r0 = 2*tid;
    float acc[KWIN][TB][2];
    const float bi0 = b_ih[r0], bi1v = b_ih[r0+1];
    #pragma unroll
    for (int t = 0; t < KWIN; ++t)
      #pragma unroll
      for (int bb = 0; bb < TB; ++bb) { acc[t][bb][0] = bi0; acc[t][bb][1] = bi1v; }
    const float* w = WihT + r0;
    for (int k4 = 0; k4 < DIN_; k4 += 4) {
      float2 w0 = *(const float2*)&w[(size_t)(k4+0)*384];
      float2 w1 = *(const float2*)&w[(size_t)(k4+1)*384];
      float2 w2 = *(const float2*)&w[(size_t)(k4+2)*384];
      float2 w3 = *(const float2*)&w[(size_t)(k4+3)*384];
      #pragma unroll
      for (int t = 0; t < KWIN; ++t)
        #pragma unroll
        for (int bb = 0; bb < TB; ++bb) {
          float4 x = *(const float4*)&xk[bb][t][k4];
          acc[t][bb][0] += w0.x*x.x + w1.x*x.y + w2.x*x.z + w3.x*x.w;
          acc[t][bb][1] += w0.y*x.x + w1.y*x.y + w2.y*x.z + w3.y*x.w;
        }
    }
    #pragma unroll
    for (int t = 0; t < KWIN; ++t)
      #pragma unroll
      for (int bb = 0; bb < TB; ++bb) {
        float2 o; o.x = acc[t][bb][0]; o.y = acc[t][bb][1];
        *(float2*)&G[(size_t)(t*TB+bb)*384 + r0] = o;
      }
  }
  __syncthreads();

  // ---- Phase B: 5 recurrent steps, WhhT read once per block per step
  int cur = 0;
  for (int t = 0; t < KWIN; ++t) {
    if (tid < 192) {
      const int r0 = 2*tid;
      float acc[TB][2];
      const float bh0 = b_hh[r0], bh1 = b_hh[r0+1];
      #pragma unroll
      for (int bb = 0; bb < TB; ++bb) { acc[bb][0] = bh0; acc[bb][1] = bh1; }
      const float* w = WhhT + r0;
      for (int k4 = 0; k4 < DCTX_; k4 += 4) {
        float2 w0 = *(const float2*)&w[(size_t)(k4+0)*384];
        float2 w1 = *(const float2*)&w[(size_t)(k4+1)*384];
        float2 w2 = *(const float2*)&w[(size_t)(k4+2)*384];
        float2 w3 = *(const float2*)&w[(size_t)(k4+3)*384];
        #pragma unroll
        for (int bb = 0; bb < TB; ++bb) {
          float4 x = *(const float4*)&hbuf[cur][bb][k4];
          acc[bb][0] += w0.x*x.x + w1.x*x.y + w2.x*x.z + w3.x*x.w;
          acc[bb][1] += w0.y*x.x + w1.y*x.y + w2.y*x.z + w3.y*x.w;
        }
      }
      #pragma unroll
      for (int bb = 0; bb < TB; ++bb) {
        float2 o; o.x = acc[bb][0]; o.y = acc[bb][1];
        *(float2*)&Hacc[bb][r0] = o;
      }
    }
    __syncthreads();
    // gate nonlinearity: 128 j x 4 bb = 512 items over 256 threads
    {
      const int j   = tid & 127;
      const int bb0 = (tid >> 7) * 2;
      #pragma unroll
      for (int e = 0; e < 2; ++e) {
        int bb = bb0 + e;
        const float* g = &G[(size_t)(t*TB+bb)*384];
        float i_r = g[j], i_z = g[128+j], i_n = g[256+j];
        float h_r = Hacc[bb][j], h_z = Hacc[bb][128+j], h_n = Hacc[bb][256+j];
        float r  = sigm(i_r + h_r);
        float zg = sigm(i_z + h_z);
        float n  = tanhf(i_n + r*h_n);
        hbuf[1-cur][bb][j] = (1.f - zg)*n + zg*hbuf[cur][bb][j];
      }
    }
    __syncthreads();
    cur ^= 1;
  }
  const float (*hf)[DCTX_] = hbuf[cur];

  // ---- Phase C: heads in parallel across waves
  if (tid < 64) {
    // u_t = bt1 + Wt1[:,0:128]@last_text + Wt1[:,256:384]@h
    const int j0 = 2*tid;
    float acc[TB][2];
    const float bb0v = bt1[j0], bb1v = bt1[j0+1];
    #pragma unroll
    for (int bb = 0; bb < TB; ++bb) { acc[bb][0] = bb0v; acc[bb][1] = bb1v; }
    const float* w = Wt1uT + j0;
    for (int k4 = 0; k4 < 128; k4 += 4) {
      float2 w0 = *(const float2*)&w[(size_t)(k4+0)*128];
      float2 w1 = *(const float2*)&w[(size_t)(k4+1)*128];
      float2 w2 = *(const float2*)&w[(size_t)(k4+2)*128];
      float2 w3 = *(const float2*)&w[(size_t)(k4+3)*128];
      #pragma unroll
      for (int bb = 0; bb < TB; ++bb) {
        float4 x = *(const float4*)&ltext[bb][k4];
        acc[bb][0] += w0.x*x.x + w1.x*x.y + w2.x*x.z + w3.x*x.w;
        acc[bb][1] += w0.y*x.x + w1.y*x.y + w2.y*x.z + w3.y*x.w;
      }
    }
    for (int k4 = 0; k4 < 128; k4 += 4) {
      float2 w0 = *(const float2*)&w[(size_t)(128+k4+0)*128];
      float2 w1 = *(const float2*)&w[(size_t)(128+k4+1)*128];
      float2 w2 = *(const float2*)&w[(size_t)(128+k4+2)*128];
      float2 w3 = *(const float2*)&w[(size_t)(128+k4+3)*128];
      #pragma unroll
      for (int bb = 0; bb < TB; ++bb) {
        float4 x = *(const float4*)&hf[bb][k4];
        acc[bb][0] += w0.x*x.x + w1.x*x.y + w2.x*x.z + w3.x*x.w;
        acc[bb][1] += w0.y*x.x + w1.y*x.y + w2.y*x.z + w3.y*x.w;
      }
    }
    #pragma unroll
    for (int bb = 0; bb < TB; ++bb) {
      float2 o; o.x = acc[bb][0]; o.y = acc[bb][1];
      *(float2*)&u_t[((size_t)b0+bb)*HID_ + j0] = o;
    }
  } else if (tid < 128) {
    // u_i = bi1 + Wi1[:,0:64]@last_id + Wi1[:,128:256]@h
    const int j0 = 2*(tid-64);
    float acc[TB][2];
    const float bb0v = bi1[j0], bb1v = bi1[j0+1];
    #pragma unroll
    for (int bb = 0; bb < TB; ++bb) { acc[bb][0] = bb0v; acc[bb][1] = bb1v; }
    const float* w = Wi1uT + j0;
    for (int k4 = 0; k4 < 64; k4 += 4) {
      float2 w0 = *(const float2*)&w[(size_t)(k4+0)*128];
      float2 w1 = *(const float2*)&w[(size_t)(k4+1)*128];
      float2 w2 = *(const float2*)&w[(size_t)(k4+2)*128];
      float2 w3 = *(const float2*)&w[(size_t)(k4+3)*128];
      #pragma unroll
      for (int bb = 0; bb < TB; ++bb) {
        float4 x = *(const float4*)&lid[bb][k4];
        acc[bb][0] += w0.x*x.x + w1.x*x.y + w2.x*x.z + w3.x*x.w;
        acc[bb][1] += w0.y*x.x + w1.y*x.y + w2.y*x.z + w3.y*x.w;
      }
    }
    for (int k4 = 0; k4 < 128; k4 += 4) {
      float2 w0 = *(const float2*)&w[(size_t)(64+k4+0)*128];
      float2 w1 = *(const float2*)&w[(size_t)(64+k4+1)*128];
      float2 w2 = *(const float2*)&w[(size_t)(64+k4+2)*128];
      float2 w3 = *(const float2*)&w[(size_t)(64+k4+3)*128];
      #pragma unroll
      for (int bb = 0; bb < TB; ++bb) {
        float4 x = *(const float4*)&hf[bb][k4];
        acc[bb][0] += w0.x*x.x + w1.x*x.y + w2.x*x.z + w3.x*x.w;
        acc[bb][1] += w0.y*x.x + w1.y*x.y + w2.y*x.z + w3.y*x.w;
      }
    }
    #pragma unroll
    for (int bb = 0; bb < TB; ++bb) {
      float2 o; o.x = acc[bb][0]; o.y = acc[bb][1];
      *(float2*)&u_i[((size_t)b0+bb)*HID_ + j0] = o;
    }
  } else if (tid < 160) {
    // alpha hidden: 64 units, rows 2*(tid-128)
    const int u0 = 2*(tid-128);
    float acc[TB][2];
    const float bb0v = ba1[u0], bb1v = ba1[u0+1];
    #pragma unroll
    for (int bb = 0; bb < TB; ++bb) { acc[bb][0] = bb0v; acc[bb][1] = bb1v; }
    const float* w = Wa1T + u0;
    for (int k4 = 0; k4 < 128; k4 += 4) {
      float2 w0 = *(const float2*)&w[(size_t)(k4+0)*64];
      float2 w1 = *(const float2*)&w[(size_t)(k4+1)*64];
      float2 w2 = *(const float2*)&w[(size_t)(k4+2)*64];
      float2 w3 = *(const float2*)&w[(size_t)(k4+3)*64];
      #pragma unroll
      for (int bb = 0; bb < TB; ++bb) {
        float4 x = *(const float4*)&hf[bb][k4];
        acc[bb][0] += w0.x*x.x + w1.x*x.y + w2.x*x.z + w3.x*x.w;
        acc[bb][1] += w0.y*x.x + w1.y*x.y + w2.y*x.z + w3.y*x.w;
      }
    }
    #pragma unroll
    for (int bb = 0; bb < TB; ++bb) {
      a1s[bb][u0]   = fmaxf(acc[bb][0], 0.f);
      a1s[bb][u0+1] = fmaxf(acc[bb][1], 0.f);
    }
  }
  __syncthreads();
  if (tid < TB) {
    int bb = tid;
    float lg0 = ba2[0], lg1 = ba2[1], lg2 = ba2[2];
    for (int k = 0; k < 64; ++k) {
      float a = a1s[bb][k];
      lg0 += Wa2[k]*a; lg1 += Wa2[64+k]*a; lg2 += Wa2[128+k]*a;
    }
    float m  = fmaxf(lg0, fmaxf(lg1, lg2));
    float e0 = __expf(lg0-m), e1 = __expf(lg1-m), e2 = __expf(lg2-m);
    float inv = 1.f/(e0+e1+e2);
    alp[((size_t)b0+bb)*3+0] = e0*inv;
    alp[((size_t)b0+bb)*3+1] = e1*inv;
    alp[((size_t)b0+bb)*3+2] = e2*inv;
  }
}

// ---------------------------------------------------------------------------
// K2 (rewritten): per-batch candidate scoring + 3 softmaxes + mixture.
// One block per batch, 4 waves; each wave owns exactly 25 candidates
// (4*25 = 100, zero padding waste). Lane owns hidden pair j0 = 2*lane.
// Candidate rows are read DIRECTLY from global as wave-uniform float4
// broadcasts (single transaction per wave) -- no Et/Ei LDS staging, so
// LDS drops 80 KB -> ~2 KB and occupancy is VGPR-limited instead of
// 2 blocks/CU. Weights stream k-major, coalesced float2 per lane,
// amortized over 13/12-candidate register chunks.
// ---------------------------------------------------------------------------
template<int CC, int KD>
__device__ __forceinline__ void score_chunk(
    const float* __restrict__ xb,   // CC candidate rows, stride KD floats
    const float* __restrict__ wT,   // [KD][128] k-major
    int j0, int lane,
    float u0, float u1, float w20, float w21,
    float invT, float* __restrict__ out)
{
  float acc0[CC], acc1[CC];
  #pragma unroll
  for (int c = 0; c < CC; ++c) { acc0[c] = 0.f; acc1[c] = 0.f; }
  for (int k4 = 0; k4 < KD; k4 += 4) {
    float2 w0 = *(const float2*)&wT[(size_t)(k4+0)*128 + j0];
    float2 w1 = *(const float2*)&wT[(size_t)(k4+1)*128 + j0];
    float2 w2 = *(const float2*)&wT[(size_t)(k4+2)*128 + j0];
    float2 w3 = *(const float2*)&wT[(size_t)(k4+3)*128 + j0];
    #pragma unroll
    for (int c = 0; c < CC; ++c) {
      float4 x = *(const float4*)&xb[(size_t)c*KD + k4];   // wave-uniform
      acc0[c] += w0.x*x.x + w1.x*x.y + w2.x*x.z + w3.x*x.w;
      acc1[c] += w0.y*x.x + w1.y*x.y + w2.y*x.z + w3.y*x.w;
    }
  }
  #pragma unroll
  for (int c = 0; c < CC; ++c) {
    float s = w20*fmaxf(acc0[c] + u0, 0.f)
            + w21*fmaxf(acc1[c] + u1, 0.f);
    s += __shfl_xor(s, 32); s += __shfl_xor(s, 16); s += __shfl_xor(s, 8);
    s += __shfl_xor(s, 4);  s += __shfl_xor(s, 2);  s += __shfl_xor(s, 1);
    if (lane == 0) out[c] = s * invT;
  }
}

__global__ __launch_bounds__(256) void k2_score(
    const int*   __restrict__ seq_items,
    const int*   __restrict__ lengths,
    const int*   __restrict__ cand_ids,
    const float* __restrict__ cand_id_emb,
    const float* __restrict__ cand_text_emb,
    const float* __restrict__ co_table,
    const float* __restrict__ Wt1sT, const float* __restrict__ Wt2,
    const float* __restrict__ Wi1sT, const float* __restrict__ Wi2,
    const float* __restrict__ u_t, const float* __restrict__ u_i,
    const float* __restrict__ alp,
    const float* __restrict__ beta_c, const float* __restrict__ logT_c,
    const float* __restrict__ logT_t, const float* __restrict__ logT_id,
    float* __restrict__ out)
{
  __shared__ float sc[3][128];
  __shared__ float vals[128];
  __shared__ float invsum_s;

  const int tid  = threadIdx.x;
  const int b    = blockIdx.x;
  const int lane = tid & 63;
  const int wv   = tid >> 6;
  const int j0   = lane * 2;

  // ---- co-occurrence scores (small random gather, L2/L3 served)
  {
    int last_item = seq_items[(size_t)b*L_ + (lengths[b]-1)];
    float scale_c = beta_c[0] * __expf(-logT_c[0]);
    for (int c = tid; c < C_; c += 256) {
      int cid = cand_ids[(size_t)b*C_ + c];
      sc[0][c] = co_table[(size_t)last_item*V_ + cid] * scale_c;
    }
  }

  // ---- per-lane constants (replaces former LDS staging of u/w2)
  const float invTt = __expf(-logT_t[0]);
  const float invTi = __expf(-logT_id[0]);
  const float ut0 = u_t[(size_t)b*HID_ + j0], ut1 = u_t[(size_t)b*HID_ + j0 + 1];
  const float ui0 = u_i[(size_t)b*HID_ + j0], ui1 = u_i[(size_t)b*HID_ + j0 + 1];
  const float wt20 = Wt2[j0], wt21 = Wt2[j0+1];
  const float wi20 = Wi2[j0], wi21 = Wi2[j0+1];

  // ---- this wave's 25 candidates
  const int c0 = wv * 25;
  const float* Et_base = cand_text_emb + ((size_t)b*C_ + c0)*DTXT_;
  const float* Ei_base = cand_id_emb   + ((size_t)b*C_ + c0)*DID_;

  // text scorer: 13 + 12 candidate chunks over K=128
  score_chunk<13, DTXT_>(Et_base,            Wt1sT, j0, lane, ut0, ut1, wt20, wt21, invTt, &sc[1][c0]);
  score_chunk<12, DTXT_>(Et_base + 13*DTXT_, Wt1sT, j0, lane, ut0, ut1, wt20, wt21, invTt, &sc[1][c0+13]);
  // id scorer: 13 + 12 candidate chunks over K=64
  score_chunk<13, DID_ >(Ei_base,            Wi1sT, j0, lane, ui0, ui1, wi20, wi21, invTi, &sc[2][c0]);
  score_chunk<12, DID_ >(Ei_base + 13*DID_,  Wi1sT, j0, lane, ui0, ui1, wi20, wi21, invTi, &sc[2][c0+13]);
  __syncthreads();

  // ---- three softmaxes over C=100, one wave each
  if (wv < 3) {
    float* s = sc[wv];
    float v0 = s[lane];
    float v1 = (lane+64 < C_) ? s[lane+64] : -3.0e38f;
    float m = fmaxf(v0, v1);
    #pragma unroll
    for (int msk = 32; msk >= 1; msk >>= 1) m = fmaxf(m, __shfl_xor(m, msk));
    float e0 = __expf(v0 - m);
    float e1 = (lane+64 < C_) ? __expf(v1 - m) : 0.f;
    float su = e0 + e1;
    #pragma unroll
    for (int msk = 32; msk >= 1; msk >>= 1) su += __shfl_xor(su, msk);
    float inv = 1.f/su;
    s[lane] = e0*inv;
    if (lane+64 < C_) s[lane+64] = e1*inv;
  }
  __syncthreads();

  // ---- mix: P = (1/C + a0*Pc + a1*Pt + a2*Pid), then renormalize
  const float a0 = alp[(size_t)b*3+0];
  const float a1 = alp[(size_t)b*3+1];
  const float a2 = alp[(size_t)b*3+2];
  float v = 0.f;
  if (tid < C_) {
    v = 0.01f + a0*sc[0][tid] + a1*sc[1][tid] + a2*sc[2][tid];
    vals[tid] = v;
  }
  __syncthreads();
  if (tid < 64) {
    float x = vals[tid] + ((tid+64 < C_) ? vals[tid+64] : 0.f);
    #pragma unroll
    for (int msk = 32; msk >= 1; msk >>= 1) x += __shfl_xor(x, msk);
    if (tid == 0) invsum_s = 1.f/x;
  }
  __syncthreads();
  if (tid < C_) out[(size_t)b*C_ + tid] = v * invsum_s;
}

// ---------------------------------------------------------------------------
extern "C" void kernel_launch(void* const* d_in, const int* in_sizes, int n_in,
                              void* d_out, int out_size, void* d_ws, size_t ws_size,
                              hipStream_t stream) {
  const int*   seq_items     = (const int*)  d_in[0];
  const float* seq_id_emb    = (const float*)d_in[1];
  const float* seq_text_emb  = (const float*)d_in[2];
  const int*   lengths       = (const int*)  d_in[3];
  const int*   cand_ids      = (const int*)  d_in[4];
  const float* cand_id_emb   = (const float*)d_in[5];
  const float* cand_text_emb = (const float*)d_in[6];
  const float* co_table      = (const float*)d_in[7];
  const float* W_ih          = (const float*)d_in[8];
  const float* W_hh          = (const float*)d_in[9];
  const float* b_ih          = (const float*)d_in[10];
  const float* b_hh          = (const float*)d_in[11];
  const float* Wt1           = (const float*)d_in[12];
  const float* bt1           = (const float*)d_in[13];
  const float* Wt2           = (const float*)d_in[14];
  const float* Wi1           = (const float*)d_in[16];
  const float* bi1           = (const float*)d_in[17];
  const float* Wi2           = (const float*)d_in[18];
  const float* Wa1           = (const float*)d_in[20];
  const float* ba1           = (const float*)d_in[21];
  const float* Wa2           = (const float*)d_in[22];
  const float* ba2           = (const float*)d_in[23];
  const float* beta_c        = (const float*)d_in[25];
  const float* logT_c        = (const float*)d_in[26];
  const float* logT_t        = (const float*)d_in[27];
  const float* logT_id       = (const float*)d_in[28];
  float* out = (float*)d_out;

  float* p = (float*)d_ws;
  float* u_t   = p; p += (size_t)B_*HID_;
  float* u_i   = p; p += (size_t)B_*HID_;
  float* alp   = p; p += (size_t)B_*3;
  float* WihT  = p; p += 192*384;
  float* WhhT  = p; p += 128*384;
  float* Wt1uT = p; p += 256*128;
  float* Wt1sT = p; p += 128*128;
  float* Wi1uT = p; p += 192*128;
  float* Wi1sT = p; p += 64*128;
  float* Wa1T  = p; p += 128*64;

  k0_transpose<<<128, 256, 0, stream>>>(
      W_ih, W_hh, Wt1, Wi1, Wa1,
      WihT, WhhT, Wt1uT, Wt1sT, Wi1uT, Wi1sT, Wa1T);

  k1_gru<<<B_/TB, 256, 0, stream>>>(
      lengths, seq_id_emb, seq_text_emb,
      WihT, WhhT, b_ih, b_hh,
      Wt1uT, bt1, Wi1uT, bi1, Wa1T, ba1, Wa2, ba2,
      u_t, u_i, alp);

  k2_score<<<B_, 256, 0, stream>>>(
      seq_items, lengths, cand_ids,
      cand_id_emb, cand_text_emb, co_table,
      Wt1sT, Wt2, Wi1sT, Wi2,
      u_t, u_i, alp,
      beta_c, logT_c, logT_t, logT_id,
      out);
}

// Round 3
// 822.507 us; speedup vs baseline: 1.1839x; 1.1839x over previous
//
#include <hip/hip_runtime.h>
#include <hip/hip_bf16.h>

// Problem constants (match reference setup_inputs)
constexpr int B_   = 2048;
constexpr int L_   = 200;
constexpr int C_   = 100;
constexpr int DID_ = 64;
constexpr int DTXT_= 128;
constexpr int DCTX_= 128;
constexpr int KWIN = 5;
constexpr int V_   = 2000;
constexpr int DIN_ = DID_ + DTXT_;   // 192
constexpr int HID_ = 128;
constexpr int TB   = 4;              // batches per k1 block

// ---------------------------------------------------------------------------
// ws layout (floats): u_t B*128 | u_i B*128 | alp B*3 | WihT 192*384 |
// WhhT 128*384 | Wt1uT 256*128 | Wt1sT 128*128 | Wi1uT 192*128 |
// Wi1sT 64*128 | Wa1T 128*64
// k-major transposes: WT[k*rows + row] = W[row*K + k]

__global__ __launch_bounds__(256) void k0_transpose(
    const float* __restrict__ W_ih, const float* __restrict__ W_hh,
    const float* __restrict__ Wt1,  const float* __restrict__ Wi1,
    const float* __restrict__ Wa1,
    float* __restrict__ WihT,  float* __restrict__ WhhT,
    float* __restrict__ Wt1uT, float* __restrict__ Wt1sT,
    float* __restrict__ Wi1uT, float* __restrict__ Wi1sT,
    float* __restrict__ Wa1T)
{
  int idx = blockIdx.x*256 + threadIdx.x;
  int stride = gridDim.x*256;
  for (int i = idx; i < 192*384; i += stride) {
    int k = i/384, r = i%384; WihT[i] = W_ih[r*192 + k];
  }
  for (int i = idx; i < 128*384; i += stride) {
    int k = i/384, r = i%384; WhhT[i] = W_hh[r*128 + k];
  }
  for (int i = idx; i < 256*128; i += stride) {
    int k = i/128, j = i%128;
    Wt1uT[i] = (k < 128) ? Wt1[j*384 + k] : Wt1[j*384 + 256 + (k-128)];
  }
  for (int i = idx; i < 128*128; i += stride) {
    int k = i/128, j = i%128; Wt1sT[i] = Wt1[j*384 + 128 + k];
  }
  for (int i = idx; i < 192*128; i += stride) {
    int k = i/128, j = i%128;
    Wi1uT[i] = (k < 64) ? Wi1[j*256 + k] : Wi1[j*256 + 128 + (k-64)];
  }
  for (int i = idx; i < 64*128; i += stride) {
    int k = i/128, j = i%128; Wi1sT[i] = Wi1[j*256 + 64 + k];
  }
  for (int i = idx; i < 128*64; i += stride) {
    int k = i/64, u = i%64; Wa1T[i] = Wa1[u*128 + k];
  }
}

__device__ __forceinline__ float sigm(float x) { return 1.f/(1.f + __expf(-x)); }

// ---------------------------------------------------------------------------
// K1: GRU + heads, weight reads amortized over TB batches and (for W_ih) all
// 5 timesteps. Thread tid<192 owns output-row pair r0=2tid of the 384 rows.
// Weights streamed k-major (coalesced, once per block per use); activations
// broadcast from LDS (wave-uniform b128 reads, conflict-free).
// ---------------------------------------------------------------------------
__global__ __launch_bounds__(256) void k1_gru(
    const int*   __restrict__ lengths,
    const float* __restrict__ seq_id,
    const float* __restrict__ seq_text,
    const float* __restrict__ WihT, const float* __restrict__ WhhT,
    const float* __restrict__ b_ih, const float* __restrict__ b_hh,
    const float* __restrict__ Wt1uT, const float* __restrict__ bt1,
    const float* __restrict__ Wi1uT, const float* __restrict__ bi1,
    const float* __restrict__ Wa1T,  const float* __restrict__ ba1,
    const float* __restrict__ Wa2,   const float* __restrict__ ba2,
    float* __restrict__ u_t, float* __restrict__ u_i,
    float* __restrict__ alp)
{
  __shared__ float xk[TB][KWIN][DIN_];       // 15360 B
  __shared__ float G[KWIN*TB*384];           // 30720 B  input projections
  __shared__ float Hacc[TB][384];            //  6144 B  per-t hidden proj
  __shared__ float hbuf[2][TB][DCTX_];       //  4096 B
  __shared__ float ltext[TB][DTXT_];         //  2048 B
  __shared__ float lid[TB][DID_];            //  1024 B
  __shared__ float a1s[TB][64];              //  1024 B
  __shared__ int   s_start[TB], s_last[TB];

  const int tid = threadIdx.x;
  const int b0  = blockIdx.x * TB;

  if (tid < TB) {
    int len = lengths[b0 + tid];
    s_start[tid] = len - KWIN;
    s_last[tid]  = len - 1;
  }
  __syncthreads();

  // ---- stage inputs (coalesced float4 within rows)
  for (int i = tid; i < TB*KWIN*(DID_/4); i += 256) {
    int bb = i/(KWIN*16), r = i%(KWIN*16), t = r/16, q = r%16;
    ((float4*)&xk[bb][t][0])[q] =
      ((const float4*)(seq_id + ((size_t)(b0+bb)*L_ + s_start[bb]+t)*DID_))[q];
  }
  for (int i = tid; i < TB*KWIN*(DTXT_/4); i += 256) {
    int bb = i/(KWIN*32), r = i%(KWIN*32), t = r/32, q = r%32;
    ((float4*)&xk[bb][t][DID_])[q] =
      ((const float4*)(seq_text + ((size_t)(b0+bb)*L_ + s_start[bb]+t)*DTXT_))[q];
  }
  for (int i = tid; i < TB*(DTXT_/4); i += 256) {
    int bb = i/32, q = i%32;
    ((float4*)ltext[bb])[q] =
      ((const float4*)(seq_text + ((size_t)(b0+bb)*L_ + s_last[bb])*DTXT_))[q];
  }
  for (int i = tid; i < TB*(DID_/4); i += 256) {
    int bb = i/16, q = i%16;
    ((float4*)lid[bb])[q] =
      ((const float4*)(seq_id + ((size_t)(b0+bb)*L_ + s_last[bb])*DID_))[q];
  }
  for (int i = tid; i < TB*DCTX_; i += 256) ((float*)hbuf[0])[i] = 0.f;
  __syncthreads();

  // ---- Phase A: input projections for all 5 steps, WihT read ONCE per block
  if (tid < 192) {
    const int r0 = 2*tid;
    float acc[KWIN][TB][2];
    const float bi0 = b_ih[r0], bi1v = b_ih[r0+1];
    #pragma unroll
    for (int t = 0; t < KWIN; ++t)
      #pragma unroll
      for (int bb = 0; bb < TB; ++bb) { acc[t][bb][0] = bi0; acc[t][bb][1] = bi1v; }
    const float* w = WihT + r0;
    for (int k4 = 0; k4 < DIN_; k4 += 4) {
      float2 w0 = *(const float2*)&w[(size_t)(k4+0)*384];
      float2 w1 = *(const float2*)&w[(size_t)(k4+1)*384];
      float2 w2 = *(const float2*)&w[(size_t)(k4+2)*384];
      float2 w3 = *(const float2*)&w[(size_t)(k4+3)*384];
      #pragma unroll
      for (int t = 0; t < KWIN; ++t)
        #pragma unroll
        for (int bb = 0; bb < TB; ++bb) {
          float4 x = *(const float4*)&xk[bb][t][k4];
          acc[t][bb][0] += w0.x*x.x + w1.x*x.y + w2.x*x.z + w3.x*x.w;
          acc[t][bb][1] += w0.y*x.x + w1.y*x.y + w2.y*x.z + w3.y*x.w;
        }
    }
    #pragma unroll
    for (int t = 0; t < KWIN; ++t)
      #pragma unroll
      for (int bb = 0; bb < TB; ++bb) {
        float2 o; o.x = acc[t][bb][0]; o.y = acc[t][bb][1];
        *(float2*)&G[(size_t)(t*TB+bb)*384 + r0] = o;
      }
  }
  __syncthreads();

  // ---- Phase B: 5 recurrent steps, WhhT read once per block per step
  int cur = 0;
  for (int t = 0; t < KWIN; ++t) {
    if (tid < 192) {
      const int r0 = 2*tid;
      float acc[TB][2];
      const float bh0 = b_hh[r0], bh1 = b_hh[r0+1];
      #pragma unroll
      for (int bb = 0; bb < TB; ++bb) { acc[bb][0] = bh0; acc[bb][1] = bh1; }
      const float* w = WhhT + r0;
      for (int k4 = 0; k4 < DCTX_; k4 += 4) {
        float2 w0 = *(const float2*)&w[(size_t)(k4+0)*384];
        float2 w1 = *(const float2*)&w[(size_t)(k4+1)*384];
        float2 w2 = *(const float2*)&w[(size_t)(k4+2)*384];
        float2 w3 = *(const float2*)&w[(size_t)(k4+3)*384];
        #pragma unroll
        for (int bb = 0; bb < TB; ++bb) {
          float4 x = *(const float4*)&hbuf[cur][bb][k4];
          acc[bb][0] += w0.x*x.x + w1.x*x.y + w2.x*x.z + w3.x*x.w;
          acc[bb][1] += w0.y*x.x + w1.y*x.y + w2.y*x.z + w3.y*x.w;
        }
      }
      #pragma unroll
      for (int bb = 0; bb < TB; ++bb) {
        float2 o; o.x = acc[bb][0]; o.y = acc[bb][1];
        *(float2*)&Hacc[bb][r0] = o;
      }
    }
    __syncthreads();
    // gate nonlinearity: 128 j x 4 bb = 512 items over 256 threads
    {
      const int j   = tid & 127;
      const int bb0 = (tid >> 7) * 2;
      #pragma unroll
      for (int e = 0; e < 2; ++e) {
        int bb = bb0 + e;
        const float* g = &G[(size_t)(t*TB+bb)*384];
        float i_r = g[j], i_z = g[128+j], i_n = g[256+j];
        float h_r = Hacc[bb][j], h_z = Hacc[bb][128+j], h_n = Hacc[bb][256+j];
        float r  = sigm(i_r + h_r);
        float zg = sigm(i_z + h_z);
        float n  = tanhf(i_n + r*h_n);
        hbuf[1-cur][bb][j] = (1.f - zg)*n + zg*hbuf[cur][bb][j];
      }
    }
    __syncthreads();
    cur ^= 1;
  }
  const float (*hf)[DCTX_] = hbuf[cur];

  // ---- Phase C: heads in parallel across waves
  if (tid < 64) {
    // u_t = bt1 + Wt1[:,0:128]@last_text + Wt1[:,256:384]@h
    const int j0 = 2*tid;
    float acc[TB][2];
    const float bb0v = bt1[j0], bb1v = bt1[j0+1];
    #pragma unroll
    for (int bb = 0; bb < TB; ++bb) { acc[bb][0] = bb0v; acc[bb][1] = bb1v; }
    const float* w = Wt1uT + j0;
    for (int k4 = 0; k4 < 128; k4 += 4) {
      float2 w0 = *(const float2*)&w[(size_t)(k4+0)*128];
      float2 w1 = *(const float2*)&w[(size_t)(k4+1)*128];
      float2 w2 = *(const float2*)&w[(size_t)(k4+2)*128];
      float2 w3 = *(const float2*)&w[(size_t)(k4+3)*128];
      #pragma unroll
      for (int bb = 0; bb < TB; ++bb) {
        float4 x = *(const float4*)&ltext[bb][k4];
        acc[bb][0] += w0.x*x.x + w1.x*x.y + w2.x*x.z + w3.x*x.w;
        acc[bb][1] += w0.y*x.x + w1.y*x.y + w2.y*x.z + w3.y*x.w;
      }
    }
    for (int k4 = 0; k4 < 128; k4 += 4) {
      float2 w0 = *(const float2*)&w[(size_t)(128+k4+0)*128];
      float2 w1 = *(const float2*)&w[(size_t)(128+k4+1)*128];
      float2 w2 = *(const float2*)&w[(size_t)(128+k4+2)*128];
      float2 w3 = *(const float2*)&w[(size_t)(128+k4+3)*128];
      #pragma unroll
      for (int bb = 0; bb < TB; ++bb) {
        float4 x = *(const float4*)&hf[bb][k4];
        acc[bb][0] += w0.x*x.x + w1.x*x.y + w2.x*x.z + w3.x*x.w;
        acc[bb][1] += w0.y*x.x + w1.y*x.y + w2.y*x.z + w3.y*x.w;
      }
    }
    #pragma unroll
    for (int bb = 0; bb < TB; ++bb) {
      float2 o; o.x = acc[bb][0]; o.y = acc[bb][1];
      *(float2*)&u_t[((size_t)b0+bb)*HID_ + j0] = o;
    }
  } else if (tid < 128) {
    // u_i = bi1 + Wi1[:,0:64]@last_id + Wi1[:,128:256]@h
    const int j0 = 2*(tid-64);
    float acc[TB][2];
    const float bb0v = bi1[j0], bb1v = bi1[j0+1];
    #pragma unroll
    for (int bb = 0; bb < TB; ++bb) { acc[bb][0] = bb0v; acc[bb][1] = bb1v; }
    const float* w = Wi1uT + j0;
    for (int k4 = 0; k4 < 64; k4 += 4) {
      float2 w0 = *(const float2*)&w[(size_t)(k4+0)*128];
      float2 w1 = *(const float2*)&w[(size_t)(k4+1)*128];
      float2 w2 = *(const float2*)&w[(size_t)(k4+2)*128];
      float2 w3 = *(const float2*)&w[(size_t)(k4+3)*128];
      #pragma unroll
      for (int bb = 0; bb < TB; ++bb) {
        float4 x = *(const float4*)&lid[bb][k4];
        acc[bb][0] += w0.x*x.x + w1.x*x.y + w2.x*x.z + w3.x*x.w;
        acc[bb][1] += w0.y*x.x + w1.y*x.y + w2.y*x.z + w3.y*x.w;
      }
    }
    for (int k4 = 0; k4 < 128; k4 += 4) {
      float2 w0 = *(const float2*)&w[(size_t)(64+k4+0)*128];
      float2 w1 = *(const float2*)&w[(size_t)(64+k4+1)*128];
      float2 w2 = *(const float2*)&w[(size_t)(64+k4+2)*128];
      float2 w3 = *(const float2*)&w[(size_t)(64+k4+3)*128];
      #pragma unroll
      for (int bb = 0; bb < TB; ++bb) {
        float4 x = *(const float4*)&hf[bb][k4];
        acc[bb][0] += w0.x*x.x + w1.x*x.y + w2.x*x.z + w3.x*x.w;
        acc[bb][1] += w0.y*x.x + w1.y*x.y + w2.y*x.z + w3.y*x.w;
      }
    }
    #pragma unroll
    for (int bb = 0; bb < TB; ++bb) {
      float2 o; o.x = acc[bb][0]; o.y = acc[bb][1];
      *(float2*)&u_i[((size_t)b0+bb)*HID_ + j0] = o;
    }
  } else if (tid < 160) {
    // alpha hidden: 64 units, rows 2*(tid-128)
    const int u0 = 2*(tid-128);
    float acc[TB][2];
    const float bb0v = ba1[u0], bb1v = ba1[u0+1];
    #pragma unroll
    for (int bb = 0; bb < TB; ++bb) { acc[bb][0] = bb0v; acc[bb][1] = bb1v; }
    const float* w = Wa1T + u0;
    for (int k4 = 0; k4 < 128; k4 += 4) {
      float2 w0 = *(const float2*)&w[(size_t)(k4+0)*64];
      float2 w1 = *(const float2*)&w[(size_t)(k4+1)*64];
      float2 w2 = *(const float2*)&w[(size_t)(k4+2)*64];
      float2 w3 = *(const float2*)&w[(size_t)(k4+3)*64];
      #pragma unroll
      for (int bb = 0; bb < TB; ++bb) {
        float4 x = *(const float4*)&hf[bb][k4];
        acc[bb][0] += w0.x*x.x + w1.x*x.y + w2.x*x.z + w3.x*x.w;
        acc[bb][1] += w0.y*x.x + w1.y*x.y + w2.y*x.z + w3.y*x.w;
      }
    }
    #pragma unroll
    for (int bb = 0; bb < TB; ++bb) {
      a1s[bb][u0]   = fmaxf(acc[bb][0], 0.f);
      a1s[bb][u0+1] = fmaxf(acc[bb][1], 0.f);
    }
  }
  __syncthreads();
  if (tid < TB) {
    int bb = tid;
    float lg0 = ba2[0], lg1 = ba2[1], lg2 = ba2[2];
    for (int k = 0; k < 64; ++k) {
      float a = a1s[bb][k];
      lg0 += Wa2[k]*a; lg1 += Wa2[64+k]*a; lg2 += Wa2[128+k]*a;
    }
    float m  = fmaxf(lg0, fmaxf(lg1, lg2));
    float e0 = __expf(lg0-m), e1 = __expf(lg1-m), e2 = __expf(lg2-m);
    float inv = 1.f/(e0+e1+e2);
    alp[((size_t)b0+bb)*3+0] = e0*inv;
    alp[((size_t)b0+bb)*3+1] = e1*inv;
    alp[((size_t)b0+bb)*3+2] = e2*inv;
  }
}

// ---------------------------------------------------------------------------
// K2 v3: LDS-broadcast x-reads (round-0 instruction mix) + zero-waste 25
// cands/wave split (round-1 layout) + small K-slab LDS tiling for occupancy.
// One block per batch, 4 waves. Wave wv owns candidates wv*25..+24; lane
// owns hidden pair j0=2*lane. Three phases reuse ONE 25.6 KB LDS slab:
//   phase 0: text rows k[0:64)   phase 1: text rows k[64:128)  (acc persists)
//   phase 2: id rows k[0:64)
// LDS ~28 KB -> 5 blocks/CU (20 waves/CU) vs round-0's 2 blocks/CU.
// ---------------------------------------------------------------------------
__device__ __forceinline__ void accum25(
    const float* __restrict__ xs_c0,   // &xs[c0*64], candidate stride 64
    const float* __restrict__ wT,      // &W[koff*128 + j0], stride 128 per k
    float* __restrict__ acc0, float* __restrict__ acc1)
{
  for (int k4 = 0; k4 < 64; k4 += 4) {
    float2 w0 = *(const float2*)&wT[(size_t)(k4+0)*128];
    float2 w1 = *(const float2*)&wT[(size_t)(k4+1)*128];
    float2 w2 = *(const float2*)&wT[(size_t)(k4+2)*128];
    float2 w3 = *(const float2*)&wT[(size_t)(k4+3)*128];
    #pragma unroll
    for (int c = 0; c < 25; ++c) {
      float4 x = *(const float4*)&xs_c0[c*64 + k4];   // wave-uniform LDS bcast
      acc0[c] += w0.x*x.x + w1.x*x.y + w2.x*x.z + w3.x*x.w;
      acc1[c] += w0.y*x.x + w1.y*x.y + w2.y*x.z + w3.y*x.w;
    }
  }
}

__global__ __launch_bounds__(256) void k2_score(
    const int*   __restrict__ seq_items,
    const int*   __restrict__ lengths,
    const int*   __restrict__ cand_ids,
    const float* __restrict__ cand_id_emb,
    const float* __restrict__ cand_text_emb,
    const float* __restrict__ co_table,
    const float* __restrict__ Wt1sT, const float* __restrict__ Wt2,
    const float* __restrict__ Wi1sT, const float* __restrict__ Wi2,
    const float* __restrict__ u_t, const float* __restrict__ u_i,
    const float* __restrict__ alp,
    const float* __restrict__ beta_c, const float* __restrict__ logT_c,
    const float* __restrict__ logT_t, const float* __restrict__ logT_id,
    float* __restrict__ out)
{
  __shared__ float xs[C_*64];          // 25600 B slab, reused 3 phases
  __shared__ float sc[3][128];
  __shared__ float vals[128];
  __shared__ float invsum_s;

  const int tid  = threadIdx.x;
  const int b    = blockIdx.x;
  const int lane = tid & 63;
  const int wv   = tid >> 6;
  const int j0   = lane * 2;

  // ---- co-occurrence scores (small random gather, L2/L3 served)
  {
    int last_item = seq_items[(size_t)b*L_ + (lengths[b]-1)];
    float scale_c = beta_c[0] * __expf(-logT_c[0]);
    for (int c = tid; c < C_; c += 256) {
      int cid = cand_ids[(size_t)b*C_ + c];
      sc[0][c] = co_table[(size_t)last_item*V_ + cid] * scale_c;
    }
  }

  // ---- per-lane constants
  const float invTt = __expf(-logT_t[0]);
  const float invTi = __expf(-logT_id[0]);
  const float ut0 = u_t[(size_t)b*HID_ + j0], ut1 = u_t[(size_t)b*HID_ + j0 + 1];
  const float ui0 = u_i[(size_t)b*HID_ + j0], ui1 = u_i[(size_t)b*HID_ + j0 + 1];
  const float wt20 = Wt2[j0], wt21 = Wt2[j0+1];
  const float wi20 = Wi2[j0], wi21 = Wi2[j0+1];

  const int c0 = wv * 25;
  float a0_[25], a1_[25];
  #pragma unroll
  for (int c = 0; c < 25; ++c) { a0_[c] = 0.f; a1_[c] = 0.f; }

  const float* Etb = cand_text_emb + (size_t)b*C_*DTXT_;

  // ---- phase 0: text k[0:64)
  for (int i = tid; i < C_*16; i += 256) {
    int c = i >> 4, q = i & 15;
    ((float4*)xs)[i] = *(const float4*)&Etb[(size_t)c*DTXT_ + 4*q];
  }
  __syncthreads();
  accum25(&xs[c0*64], Wt1sT + j0, a0_, a1_);
  __syncthreads();

  // ---- phase 1: text k[64:128)
  for (int i = tid; i < C_*16; i += 256) {
    int c = i >> 4, q = i & 15;
    ((float4*)xs)[i] = *(const float4*)&Etb[(size_t)c*DTXT_ + 64 + 4*q];
  }
  __syncthreads();
  accum25(&xs[c0*64], Wt1sT + (size_t)64*128 + j0, a0_, a1_);
  // text epilogue (reads registers + sc only, not xs)
  #pragma unroll
  for (int c = 0; c < 25; ++c) {
    float s = wt20*fmaxf(a0_[c] + ut0, 0.f)
            + wt21*fmaxf(a1_[c] + ut1, 0.f);
    s += __shfl_xor(s, 32); s += __shfl_xor(s, 16); s += __shfl_xor(s, 8);
    s += __shfl_xor(s, 4);  s += __shfl_xor(s, 2);  s += __shfl_xor(s, 1);
    if (lane == 0) sc[1][c0+c] = s * invTt;
  }
  __syncthreads();

  // ---- phase 2: id (all 100 rows x 64 = same slab size, contiguous copy)
  {
    const float4* Eib = (const float4*)(cand_id_emb + (size_t)b*C_*DID_);
    for (int i = tid; i < C_*16; i += 256) ((float4*)xs)[i] = Eib[i];
  }
  #pragma unroll
  for (int c = 0; c < 25; ++c) { a0_[c] = 0.f; a1_[c] = 0.f; }
  __syncthreads();
  accum25(&xs[c0*64], Wi1sT + j0, a0_, a1_);
  #pragma unroll
  for (int c = 0; c < 25; ++c) {
    float s = wi20*fmaxf(a0_[c] + ui0, 0.f)
            + wi21*fmaxf(a1_[c] + ui1, 0.f);
    s += __shfl_xor(s, 32); s += __shfl_xor(s, 16); s += __shfl_xor(s, 8);
    s += __shfl_xor(s, 4);  s += __shfl_xor(s, 2);  s += __shfl_xor(s, 1);
    if (lane == 0) sc[2][c0+c] = s * invTi;
  }
  __syncthreads();

  // ---- three softmaxes over C=100, one wave each
  if (wv < 3) {
    float* s = sc[wv];
    float v0 = s[lane];
    float v1 = (lane+64 < C_) ? s[lane+64] : -3.0e38f;
    float m = fmaxf(v0, v1);
    #pragma unroll
    for (int msk = 32; msk >= 1; msk >>= 1) m = fmaxf(m, __shfl_xor(m, msk));
    float e0 = __expf(v0 - m);
    float e1 = (lane+64 < C_) ? __expf(v1 - m) : 0.f;
    float su = e0 + e1;
    #pragma unroll
    for (int msk = 32; msk >= 1; msk >>= 1) su += __shfl_xor(su, msk);
    float inv = 1.f/su;
    s[lane] = e0*inv;
    if (lane+64 < C_) s[lane+64] = e1*inv;
  }
  __syncthreads();

  // ---- mix: P = (1/C + a0*Pc + a1*Pt + a2*Pid), then renormalize
  const float a0 = alp[(size_t)b*3+0];
  const float a1 = alp[(size_t)b*3+1];
  const float a2 = alp[(size_t)b*3+2];
  float v = 0.f;
  if (tid < C_) {
    v = 0.01f + a0*sc[0][tid] + a1*sc[1][tid] + a2*sc[2][tid];
    vals[tid] = v;
  }
  __syncthreads();
  if (tid < 64) {
    float x = vals[tid] + ((tid+64 < C_) ? vals[tid+64] : 0.f);
    #pragma unroll
    for (int msk = 32; msk >= 1; msk >>= 1) x += __shfl_xor(x, msk);
    if (tid == 0) invsum_s = 1.f/x;
  }
  __syncthreads();
  if (tid < C_) out[(size_t)b*C_ + tid] = v * invsum_s;
}

// ---------------------------------------------------------------------------
extern "C" void kernel_launch(void* const* d_in, const int* in_sizes, int n_in,
                              void* d_out, int out_size, void* d_ws, size_t ws_size,
                              hipStream_t stream) {
  const int*   seq_items     = (const int*)  d_in[0];
  const float* seq_id_emb    = (const float*)d_in[1];
  const float* seq_text_emb  = (const float*)d_in[2];
  const int*   lengths       = (const int*)  d_in[3];
  const int*   cand_ids      = (const int*)  d_in[4];
  const float* cand_id_emb   = (const float*)d_in[5];
  const float* cand_text_emb = (const float*)d_in[6];
  const float* co_table      = (const float*)d_in[7];
  const float* W_ih          = (const float*)d_in[8];
  const float* W_hh          = (const float*)d_in[9];
  const float* b_ih          = (const float*)d_in[10];
  const float* b_hh          = (const float*)d_in[11];
  const float* Wt1           = (const float*)d_in[12];
  const float* bt1           = (const float*)d_in[13];
  const float* Wt2           = (const float*)d_in[14];
  const float* Wi1           = (const float*)d_in[16];
  const float* bi1           = (const float*)d_in[17];
  const float* Wi2           = (const float*)d_in[18];
  const float* Wa1           = (const float*)d_in[20];
  const float* ba1           = (const float*)d_in[21];
  const float* Wa2           = (const float*)d_in[22];
  const float* ba2           = (const float*)d_in[23];
  const float* beta_c        = (const float*)d_in[25];
  const float* logT_c        = (const float*)d_in[26];
  const float* logT_t        = (const float*)d_in[27];
  const float* logT_id       = (const float*)d_in[28];
  float* out = (float*)d_out;

  float* p = (float*)d_ws;
  float* u_t   = p; p += (size_t)B_*HID_;
  float* u_i   = p; p += (size_t)B_*HID_;
  float* alp   = p; p += (size_t)B_*3;
  float* WihT  = p; p += 192*384;
  float* WhhT  = p; p += 128*384;
  float* Wt1uT = p; p += 256*128;
  float* Wt1sT = p; p += 128*128;
  float* Wi1uT = p; p += 192*128;
  float* Wi1sT = p; p += 64*128;
  float* Wa1T  = p; p += 128*64;

  k0_transpose<<<128, 256, 0, stream>>>(
      W_ih, W_hh, Wt1, Wi1, Wa1,
      WihT, WhhT, Wt1uT, Wt1sT, Wi1uT, Wi1sT, Wa1T);

  k1_gru<<<B_/TB, 256, 0, stream>>>(
      lengths, seq_id_emb, seq_text_emb,
      WihT, WhhT, b_ih, b_hh,
      Wt1uT, bt1, Wi1uT, bi1, Wa1T, ba1, Wa2, ba2,
      u_t, u_i, alp);

  k2_score<<<B_, 256, 0, stream>>>(
      seq_items, lengths, cand_ids,
      cand_id_emb, cand_text_emb, co_table,
      Wt1sT, Wt2, Wi1sT, Wi2,
      u_t, u_i, alp,
      beta_c, logT_c, logT_t, logT_id,
      out);
}

// Round 4
// 780.676 us; speedup vs baseline: 1.2473x; 1.0536x over previous
//
#include <hip/hip_runtime.h>
#include <hip/hip_bf16.h>

// Problem constants (match reference setup_inputs)
constexpr int B_   = 2048;
constexpr int L_   = 200;
constexpr int C_   = 100;
constexpr int DID_ = 64;
constexpr int DTXT_= 128;
constexpr int DCTX_= 128;
constexpr int KWIN = 5;
constexpr int V_   = 2000;
constexpr int DIN_ = DID_ + DTXT_;   // 192
constexpr int HID_ = 128;
constexpr int TB   = 2;              // batches per k1 block (v4: 4->2 for 2x grid)

// ---------------------------------------------------------------------------
// ws layout (floats): u_t B*128 | u_i B*128 | alp B*3 | WihT 192*384 |
// WhhT 128*384 | Wt1uT 256*128 | Wt1sT 128*128 | Wi1uT 192*128 |
// Wi1sT 64*128 | Wa1T 128*64
// k-major transposes: WT[k*rows + row] = W[row*K + k]

__global__ __launch_bounds__(256) void k0_transpose(
    const float* __restrict__ W_ih, const float* __restrict__ W_hh,
    const float* __restrict__ Wt1,  const float* __restrict__ Wi1,
    const float* __restrict__ Wa1,
    float* __restrict__ WihT,  float* __restrict__ WhhT,
    float* __restrict__ Wt1uT, float* __restrict__ Wt1sT,
    float* __restrict__ Wi1uT, float* __restrict__ Wi1sT,
    float* __restrict__ Wa1T)
{
  int idx = blockIdx.x*256 + threadIdx.x;
  int stride = gridDim.x*256;
  for (int i = idx; i < 192*384; i += stride) {
    int k = i/384, r = i%384; WihT[i] = W_ih[r*192 + k];
  }
  for (int i = idx; i < 128*384; i += stride) {
    int k = i/384, r = i%384; WhhT[i] = W_hh[r*128 + k];
  }
  for (int i = idx; i < 256*128; i += stride) {
    int k = i/128, j = i%128;
    Wt1uT[i] = (k < 128) ? Wt1[j*384 + k] : Wt1[j*384 + 256 + (k-128)];
  }
  for (int i = idx; i < 128*128; i += stride) {
    int k = i/128, j = i%128; Wt1sT[i] = Wt1[j*384 + 128 + k];
  }
  for (int i = idx; i < 192*128; i += stride) {
    int k = i/128, j = i%128;
    Wi1uT[i] = (k < 64) ? Wi1[j*256 + k] : Wi1[j*256 + 128 + (k-64)];
  }
  for (int i = idx; i < 64*128; i += stride) {
    int k = i/128, j = i%128; Wi1sT[i] = Wi1[j*256 + 64 + k];
  }
  for (int i = idx; i < 128*64; i += stride) {
    int k = i/64, u = i%64; Wa1T[i] = Wa1[u*128 + k];
  }
}

__device__ __forceinline__ float sigm(float x) { return 1.f/(1.f + __expf(-x)); }

// ---------------------------------------------------------------------------
// K1: GRU + heads. v4: TB=2 -> 1024 blocks (4 blocks/CU reachable vs 2),
// Phase-A acc registers halved (20 vs 40), LDS ~30 KB.
// ---------------------------------------------------------------------------
__global__ __launch_bounds__(256) void k1_gru(
    const int*   __restrict__ lengths,
    const float* __restrict__ seq_id,
    const float* __restrict__ seq_text,
    const float* __restrict__ WihT, const float* __restrict__ WhhT,
    const float* __restrict__ b_ih, const float* __restrict__ b_hh,
    const float* __restrict__ Wt1uT, const float* __restrict__ bt1,
    const float* __restrict__ Wi1uT, const float* __restrict__ bi1,
    const float* __restrict__ Wa1T,  const float* __restrict__ ba1,
    const float* __restrict__ Wa2,   const float* __restrict__ ba2,
    float* __restrict__ u_t, float* __restrict__ u_i,
    float* __restrict__ alp)
{
  __shared__ float xk[TB][KWIN][DIN_];
  __shared__ float G[KWIN*TB*384];
  __shared__ float Hacc[TB][384];
  __shared__ float hbuf[2][TB][DCTX_];
  __shared__ float ltext[TB][DTXT_];
  __shared__ float lid[TB][DID_];
  __shared__ float a1s[TB][64];
  __shared__ int   s_start[TB], s_last[TB];

  const int tid = threadIdx.x;
  const int b0  = blockIdx.x * TB;

  if (tid < TB) {
    int len = lengths[b0 + tid];
    s_start[tid] = len - KWIN;
    s_last[tid]  = len - 1;
  }
  __syncthreads();

  // ---- stage inputs (coalesced float4 within rows)
  for (int i = tid; i < TB*KWIN*(DID_/4); i += 256) {
    int bb = i/(KWIN*16), r = i%(KWIN*16), t = r/16, q = r%16;
    ((float4*)&xk[bb][t][0])[q] =
      ((const float4*)(seq_id + ((size_t)(b0+bb)*L_ + s_start[bb]+t)*DID_))[q];
  }
  for (int i = tid; i < TB*KWIN*(DTXT_/4); i += 256) {
    int bb = i/(KWIN*32), r = i%(KWIN*32), t = r/32, q = r%32;
    ((float4*)&xk[bb][t][DID_])[q] =
      ((const float4*)(seq_text + ((size_t)(b0+bb)*L_ + s_start[bb]+t)*DTXT_))[q];
  }
  for (int i = tid; i < TB*(DTXT_/4); i += 256) {
    int bb = i/32, q = i%32;
    ((float4*)ltext[bb])[q] =
      ((const float4*)(seq_text + ((size_t)(b0+bb)*L_ + s_last[bb])*DTXT_))[q];
  }
  for (int i = tid; i < TB*(DID_/4); i += 256) {
    int bb = i/16, q = i%16;
    ((float4*)lid[bb])[q] =
      ((const float4*)(seq_id + ((size_t)(b0+bb)*L_ + s_last[bb])*DID_))[q];
  }
  for (int i = tid; i < TB*DCTX_; i += 256) ((float*)hbuf[0])[i] = 0.f;
  __syncthreads();

  // ---- Phase A: input projections for all 5 steps, WihT read ONCE per block
  if (tid < 192) {
    const int r0 = 2*tid;
    float acc[KWIN][TB][2];
    const float bi0 = b_ih[r0], bi1v = b_ih[r0+1];
    #pragma unroll
    for (int t = 0; t < KWIN; ++t)
      #pragma unroll
      for (int bb = 0; bb < TB; ++bb) { acc[t][bb][0] = bi0; acc[t][bb][1] = bi1v; }
    const float* w = WihT + r0;
    for (int k4 = 0; k4 < DIN_; k4 += 4) {
      float2 w0 = *(const float2*)&w[(size_t)(k4+0)*384];
      float2 w1 = *(const float2*)&w[(size_t)(k4+1)*384];
      float2 w2 = *(const float2*)&w[(size_t)(k4+2)*384];
      float2 w3 = *(const float2*)&w[(size_t)(k4+3)*384];
      #pragma unroll
      for (int t = 0; t < KWIN; ++t)
        #pragma unroll
        for (int bb = 0; bb < TB; ++bb) {
          float4 x = *(const float4*)&xk[bb][t][k4];
          acc[t][bb][0] += w0.x*x.x + w1.x*x.y + w2.x*x.z + w3.x*x.w;
          acc[t][bb][1] += w0.y*x.x + w1.y*x.y + w2.y*x.z + w3.y*x.w;
        }
    }
    #pragma unroll
    for (int t = 0; t < KWIN; ++t)
      #pragma unroll
      for (int bb = 0; bb < TB; ++bb) {
        float2 o; o.x = acc[t][bb][0]; o.y = acc[t][bb][1];
        *(float2*)&G[(size_t)(t*TB+bb)*384 + r0] = o;
      }
  }
  __syncthreads();

  // ---- Phase B: 5 recurrent steps, WhhT read once per block per step
  int cur = 0;
  for (int t = 0; t < KWIN; ++t) {
    if (tid < 192) {
      const int r0 = 2*tid;
      float acc[TB][2];
      const float bh0 = b_hh[r0], bh1 = b_hh[r0+1];
      #pragma unroll
      for (int bb = 0; bb < TB; ++bb) { acc[bb][0] = bh0; acc[bb][1] = bh1; }
      const float* w = WhhT + r0;
      for (int k4 = 0; k4 < DCTX_; k4 += 4) {
        float2 w0 = *(const float2*)&w[(size_t)(k4+0)*384];
        float2 w1 = *(const float2*)&w[(size_t)(k4+1)*384];
        float2 w2 = *(const float2*)&w[(size_t)(k4+2)*384];
        float2 w3 = *(const float2*)&w[(size_t)(k4+3)*384];
        #pragma unroll
        for (int bb = 0; bb < TB; ++bb) {
          float4 x = *(const float4*)&hbuf[cur][bb][k4];
          acc[bb][0] += w0.x*x.x + w1.x*x.y + w2.x*x.z + w3.x*x.w;
          acc[bb][1] += w0.y*x.x + w1.y*x.y + w2.y*x.z + w3.y*x.w;
        }
      }
      #pragma unroll
      for (int bb = 0; bb < TB; ++bb) {
        float2 o; o.x = acc[bb][0]; o.y = acc[bb][1];
        *(float2*)&Hacc[bb][r0] = o;
      }
    }
    __syncthreads();
    // gate nonlinearity: 128 j x TB bb over 256 threads
    {
      const int j    = tid & 127;
      const int half = tid >> 7;                // 0 or 1
      #pragma unroll
      for (int e = 0; e < (TB+1)/2; ++e) {
        int bb = half*(TB/2) + e;
        const float* g = &G[(size_t)(t*TB+bb)*384];
        float i_r = g[j], i_z = g[128+j], i_n = g[256+j];
        float h_r = Hacc[bb][j], h_z = Hacc[bb][128+j], h_n = Hacc[bb][256+j];
        float r  = sigm(i_r + h_r);
        float zg = sigm(i_z + h_z);
        float n  = tanhf(i_n + r*h_n);
        hbuf[1-cur][bb][j] = (1.f - zg)*n + zg*hbuf[cur][bb][j];
      }
    }
    __syncthreads();
    cur ^= 1;
  }
  const float (*hf)[DCTX_] = hbuf[cur];

  // ---- Phase C: heads in parallel across waves
  if (tid < 64) {
    // u_t = bt1 + Wt1[:,0:128]@last_text + Wt1[:,256:384]@h
    const int j0 = 2*tid;
    float acc[TB][2];
    const float bb0v = bt1[j0], bb1v = bt1[j0+1];
    #pragma unroll
    for (int bb = 0; bb < TB; ++bb) { acc[bb][0] = bb0v; acc[bb][1] = bb1v; }
    const float* w = Wt1uT + j0;
    for (int k4 = 0; k4 < 128; k4 += 4) {
      float2 w0 = *(const float2*)&w[(size_t)(k4+0)*128];
      float2 w1 = *(const float2*)&w[(size_t)(k4+1)*128];
      float2 w2 = *(const float2*)&w[(size_t)(k4+2)*128];
      float2 w3 = *(const float2*)&w[(size_t)(k4+3)*128];
      #pragma unroll
      for (int bb = 0; bb < TB; ++bb) {
        float4 x = *(const float4*)&ltext[bb][k4];
        acc[bb][0] += w0.x*x.x + w1.x*x.y + w2.x*x.z + w3.x*x.w;
        acc[bb][1] += w0.y*x.x + w1.y*x.y + w2.y*x.z + w3.y*x.w;
      }
    }
    for (int k4 = 0; k4 < 128; k4 += 4) {
      float2 w0 = *(const float2*)&w[(size_t)(128+k4+0)*128];
      float2 w1 = *(const float2*)&w[(size_t)(128+k4+1)*128];
      float2 w2 = *(const float2*)&w[(size_t)(128+k4+2)*128];
      float2 w3 = *(const float2*)&w[(size_t)(128+k4+3)*128];
      #pragma unroll
      for (int bb = 0; bb < TB; ++bb) {
        float4 x = *(const float4*)&hf[bb][k4];
        acc[bb][0] += w0.x*x.x + w1.x*x.y + w2.x*x.z + w3.x*x.w;
        acc[bb][1] += w0.y*x.x + w1.y*x.y + w2.y*x.z + w3.y*x.w;
      }
    }
    #pragma unroll
    for (int bb = 0; bb < TB; ++bb) {
      float2 o; o.x = acc[bb][0]; o.y = acc[bb][1];
      *(float2*)&u_t[((size_t)b0+bb)*HID_ + j0] = o;
    }
  } else if (tid < 128) {
    // u_i = bi1 + Wi1[:,0:64]@last_id + Wi1[:,128:256]@h
    const int j0 = 2*(tid-64);
    float acc[TB][2];
    const float bb0v = bi1[j0], bb1v = bi1[j0+1];
    #pragma unroll
    for (int bb = 0; bb < TB; ++bb) { acc[bb][0] = bb0v; acc[bb][1] = bb1v; }
    const float* w = Wi1uT + j0;
    for (int k4 = 0; k4 < 64; k4 += 4) {
      float2 w0 = *(const float2*)&w[(size_t)(k4+0)*128];
      float2 w1 = *(const float2*)&w[(size_t)(k4+1)*128];
      float2 w2 = *(const float2*)&w[(size_t)(k4+2)*128];
      float2 w3 = *(const float2*)&w[(size_t)(k4+3)*128];
      #pragma unroll
      for (int bb = 0; bb < TB; ++bb) {
        float4 x = *(const float4*)&lid[bb][k4];
        acc[bb][0] += w0.x*x.x + w1.x*x.y + w2.x*x.z + w3.x*x.w;
        acc[bb][1] += w0.y*x.x + w1.y*x.y + w2.y*x.z + w3.y*x.w;
      }
    }
    for (int k4 = 0; k4 < 128; k4 += 4) {
      float2 w0 = *(const float2*)&w[(size_t)(64+k4+0)*128];
      float2 w1 = *(const float2*)&w[(size_t)(64+k4+1)*128];
      float2 w2 = *(const float2*)&w[(size_t)(64+k4+2)*128];
      float2 w3 = *(const float2*)&w[(size_t)(64+k4+3)*128];
      #pragma unroll
      for (int bb = 0; bb < TB; ++bb) {
        float4 x = *(const float4*)&hf[bb][k4];
        acc[bb][0] += w0.x*x.x + w1.x*x.y + w2.x*x.z + w3.x*x.w;
        acc[bb][1] += w0.y*x.x + w1.y*x.y + w2.y*x.z + w3.y*x.w;
      }
    }
    #pragma unroll
    for (int bb = 0; bb < TB; ++bb) {
      float2 o; o.x = acc[bb][0]; o.y = acc[bb][1];
      *(float2*)&u_i[((size_t)b0+bb)*HID_ + j0] = o;
    }
  } else if (tid < 160) {
    // alpha hidden: 64 units, rows 2*(tid-128)
    const int u0 = 2*(tid-128);
    float acc[TB][2];
    const float bb0v = ba1[u0], bb1v = ba1[u0+1];
    #pragma unroll
    for (int bb = 0; bb < TB; ++bb) { acc[bb][0] = bb0v; acc[bb][1] = bb1v; }
    const float* w = Wa1T + u0;
    for (int k4 = 0; k4 < 128; k4 += 4) {
      float2 w0 = *(const float2*)&w[(size_t)(k4+0)*64];
      float2 w1 = *(const float2*)&w[(size_t)(k4+1)*64];
      float2 w2 = *(const float2*)&w[(size_t)(k4+2)*64];
      float2 w3 = *(const float2*)&w[(size_t)(k4+3)*64];
      #pragma unroll
      for (int bb = 0; bb < TB; ++bb) {
        float4 x = *(const float4*)&hf[bb][k4];
        acc[bb][0] += w0.x*x.x + w1.x*x.y + w2.x*x.z + w3.x*x.w;
        acc[bb][1] += w0.y*x.x + w1.y*x.y + w2.y*x.z + w3.y*x.w;
      }
    }
    #pragma unroll
    for (int bb = 0; bb < TB; ++bb) {
      a1s[bb][u0]   = fmaxf(acc[bb][0], 0.f);
      a1s[bb][u0+1] = fmaxf(acc[bb][1], 0.f);
    }
  }
  __syncthreads();
  if (tid < TB) {
    int bb = tid;
    float lg0 = ba2[0], lg1 = ba2[1], lg2 = ba2[2];
    for (int k = 0; k < 64; ++k) {
      float a = a1s[bb][k];
      lg0 += Wa2[k]*a; lg1 += Wa2[64+k]*a; lg2 += Wa2[128+k]*a;
    }
    float m  = fmaxf(lg0, fmaxf(lg1, lg2));
    float e0 = __expf(lg0-m), e1 = __expf(lg1-m), e2 = __expf(lg2-m);
    float inv = 1.f/(e0+e1+e2);
    alp[((size_t)b0+bb)*3+0] = e0*inv;
    alp[((size_t)b0+bb)*3+1] = e1*inv;
    alp[((size_t)b0+bb)*3+2] = e2*inv;
  }
}

// ---------------------------------------------------------------------------
// K2 v4: full-K text slab so each candidate chunk completes (k-loop +
// epilogue) before the next -> only acc[13][2]=26 VGPRs ever live (v3's
// acc[25][2] across barriers hit VGPR=136 > 128 wave-slot boundary).
// One block per batch, 4 waves; wave wv owns cands wv*25..+24, chunks 13+12.
// Lane owns hidden pair j0=2*lane; x rows broadcast from LDS (wave-uniform
// b128, conflict-free); weights stream coalesced float2 from L2.
// LDS ~53.3 KB -> 3 blocks/CU; VGPR ~80 -> 4 waves/SIMD quantum.
// Barriers in compute path: 3 (vs v3's 6).
// ---------------------------------------------------------------------------
template<int CC, int KD>
__device__ __forceinline__ void accumN(
    const float* __restrict__ xs_c0,   // chunk base, row stride KD floats
    const float* __restrict__ wT,      // weight base + j0, row stride 128
    float* __restrict__ a0, float* __restrict__ a1)
{
  for (int k4 = 0; k4 < KD; k4 += 4) {
    float2 w0 = *(const float2*)&wT[(size_t)(k4+0)*128];
    float2 w1 = *(const float2*)&wT[(size_t)(k4+1)*128];
    float2 w2 = *(const float2*)&wT[(size_t)(k4+2)*128];
    float2 w3 = *(const float2*)&wT[(size_t)(k4+3)*128];
    #pragma unroll
    for (int c = 0; c < CC; ++c) {
      float4 x = *(const float4*)&xs_c0[c*KD + k4];   // LDS broadcast
      a0[c] += w0.x*x.x + w1.x*x.y + w2.x*x.z + w3.x*x.w;
      a1[c] += w0.y*x.x + w1.y*x.y + w2.y*x.z + w3.y*x.w;
    }
  }
}

template<int CC>
__device__ __forceinline__ void epilogueN(
    const float* __restrict__ a0, const float* __restrict__ a1,
    float u0, float u1, float w20, float w21, float invT,
    int lane, float* __restrict__ outp)
{
  #pragma unroll
  for (int c = 0; c < CC; ++c) {
    float s = w20*fmaxf(a0[c] + u0, 0.f)
            + w21*fmaxf(a1[c] + u1, 0.f);
    s += __shfl_xor(s, 32); s += __shfl_xor(s, 16); s += __shfl_xor(s, 8);
    s += __shfl_xor(s, 4);  s += __shfl_xor(s, 2);  s += __shfl_xor(s, 1);
    if (lane == 0) outp[c] = s * invT;
  }
}

__global__ __launch_bounds__(256) void k2_score(
    const int*   __restrict__ seq_items,
    const int*   __restrict__ lengths,
    const int*   __restrict__ cand_ids,
    const float* __restrict__ cand_id_emb,
    const float* __restrict__ cand_text_emb,
    const float* __restrict__ co_table,
    const float* __restrict__ Wt1sT, const float* __restrict__ Wt2,
    const float* __restrict__ Wi1sT, const float* __restrict__ Wi2,
    const float* __restrict__ u_t, const float* __restrict__ u_i,
    const float* __restrict__ alp,
    const float* __restrict__ beta_c, const float* __restrict__ logT_c,
    const float* __restrict__ logT_t, const float* __restrict__ logT_id,
    float* __restrict__ out)
{
  __shared__ float xs[C_*DTXT_];       // 51200 B: text full-K; id reuses 25.6 KB
  __shared__ float sc[3][128];
  __shared__ float vals[128];
  __shared__ float invsum_s;

  const int tid  = threadIdx.x;
  const int b    = blockIdx.x;
  const int lane = tid & 63;
  const int wv   = tid >> 6;
  const int j0   = lane * 2;

  // ---- stage text slab (linear contiguous copy, fully coalesced)
  {
    const float4* src = (const float4*)(cand_text_emb + (size_t)b*C_*DTXT_);
    for (int i = tid; i < C_*DTXT_/4; i += 256) ((float4*)xs)[i] = src[i];
  }
  // ---- co-occurrence scores (independent; overlaps with staging)
  {
    int last_item = seq_items[(size_t)b*L_ + (lengths[b]-1)];
    float scale_c = beta_c[0] * __expf(-logT_c[0]);
    for (int c = tid; c < C_; c += 256) {
      int cid = cand_ids[(size_t)b*C_ + c];
      sc[0][c] = co_table[(size_t)last_item*V_ + cid] * scale_c;
    }
  }

  // ---- per-lane constants
  const float invTt = __expf(-logT_t[0]);
  const float invTi = __expf(-logT_id[0]);
  const float ut0 = u_t[(size_t)b*HID_ + j0], ut1 = u_t[(size_t)b*HID_ + j0 + 1];
  const float ui0 = u_i[(size_t)b*HID_ + j0], ui1 = u_i[(size_t)b*HID_ + j0 + 1];
  const float wt20 = Wt2[j0], wt21 = Wt2[j0+1];
  const float wi20 = Wi2[j0], wi21 = Wi2[j0+1];

  const int c0 = wv * 25;
  float a0_[13], a1_[13];

  __syncthreads();

  // ---- text scorer: chunk A (13 cands), full K=128, then epilogue
  #pragma unroll
  for (int c = 0; c < 13; ++c) { a0_[c] = 0.f; a1_[c] = 0.f; }
  accumN<13, DTXT_>(&xs[(size_t)c0*DTXT_], Wt1sT + j0, a0_, a1_);
  epilogueN<13>(a0_, a1_, ut0, ut1, wt20, wt21, invTt, lane, &sc[1][c0]);
  // ---- text scorer: chunk B (12 cands)
  #pragma unroll
  for (int c = 0; c < 12; ++c) { a0_[c] = 0.f; a1_[c] = 0.f; }
  accumN<12, DTXT_>(&xs[(size_t)(c0+13)*DTXT_], Wt1sT + j0, a0_, a1_);
  epilogueN<12>(a0_, a1_, ut0, ut1, wt20, wt21, invTt, lane, &sc[1][c0+13]);
  __syncthreads();

  // ---- stage id slab into same LDS (contiguous 25.6 KB copy)
  {
    const float4* src = (const float4*)(cand_id_emb + (size_t)b*C_*DID_);
    for (int i = tid; i < C_*DID_/4; i += 256) ((float4*)xs)[i] = src[i];
  }
  __syncthreads();

  // ---- id scorer: chunks A/B over K=64
  #pragma unroll
  for (int c = 0; c < 13; ++c) { a0_[c] = 0.f; a1_[c] = 0.f; }
  accumN<13, DID_>(&xs[(size_t)c0*DID_], Wi1sT + j0, a0_, a1_);
  epilogueN<13>(a0_, a1_, ui0, ui1, wi20, wi21, invTi, lane, &sc[2][c0]);
  #pragma unroll
  for (int c = 0; c < 12; ++c) { a0_[c] = 0.f; a1_[c] = 0.f; }
  accumN<12, DID_>(&xs[(size_t)(c0+13)*DID_], Wi1sT + j0, a0_, a1_);
  epilogueN<12>(a0_, a1_, ui0, ui1, wi20, wi21, invTi, lane, &sc[2][c0+13]);
  __syncthreads();

  // ---- three softmaxes over C=100, one wave each
  if (wv < 3) {
    float* s = sc[wv];
    float v0 = s[lane];
    float v1 = (lane+64 < C_) ? s[lane+64] : -3.0e38f;
    float m = fmaxf(v0, v1);
    #pragma unroll
    for (int msk = 32; msk >= 1; msk >>= 1) m = fmaxf(m, __shfl_xor(m, msk));
    float e0 = __expf(v0 - m);
    float e1 = (lane+64 < C_) ? __expf(v1 - m) : 0.f;
    float su = e0 + e1;
    #pragma unroll
    for (int msk = 32; msk >= 1; msk >>= 1) su += __shfl_xor(su, msk);
    float inv = 1.f/su;
    s[lane] = e0*inv;
    if (lane+64 < C_) s[lane+64] = e1*inv;
  }
  __syncthreads();

  // ---- mix: P = (1/C + a0*Pc + a1*Pt + a2*Pid), then renormalize
  const float a0 = alp[(size_t)b*3+0];
  const float a1 = alp[(size_t)b*3+1];
  const float a2 = alp[(size_t)b*3+2];
  float v = 0.f;
  if (tid < C_) {
    v = 0.01f + a0*sc[0][tid] + a1*sc[1][tid] + a2*sc[2][tid];
    vals[tid] = v;
  }
  __syncthreads();
  if (tid < 64) {
    float x = vals[tid] + ((tid+64 < C_) ? vals[tid+64] : 0.f);
    #pragma unroll
    for (int msk = 32; msk >= 1; msk >>= 1) x += __shfl_xor(x, msk);
    if (tid == 0) invsum_s = 1.f/x;
  }
  __syncthreads();
  if (tid < C_) out[(size_t)b*C_ + tid] = v * invsum_s;
}

// ---------------------------------------------------------------------------
extern "C" void kernel_launch(void* const* d_in, const int* in_sizes, int n_in,
                              void* d_out, int out_size, void* d_ws, size_t ws_size,
                              hipStream_t stream) {
  const int*   seq_items     = (const int*)  d_in[0];
  const float* seq_id_emb    = (const float*)d_in[1];
  const float* seq_text_emb  = (const float*)d_in[2];
  const int*   lengths       = (const int*)  d_in[3];
  const int*   cand_ids      = (const int*)  d_in[4];
  const float* cand_id_emb   = (const float*)d_in[5];
  const float* cand_text_emb = (const float*)d_in[6];
  const float* co_table      = (const float*)d_in[7];
  const float* W_ih          = (const float*)d_in[8];
  const float* W_hh          = (const float*)d_in[9];
  const float* b_ih          = (const float*)d_in[10];
  const float* b_hh          = (const float*)d_in[11];
  const float* Wt1           = (const float*)d_in[12];
  const float* bt1           = (const float*)d_in[13];
  const float* Wt2           = (const float*)d_in[14];
  const float* Wi1           = (const float*)d_in[16];
  const float* bi1           = (const float*)d_in[17];
  const float* Wi2           = (const float*)d_in[18];
  const float* Wa1           = (const float*)d_in[20];
  const float* ba1           = (const float*)d_in[21];
  const float* Wa2           = (const float*)d_in[22];
  const float* ba2           = (const float*)d_in[23];
  const float* beta_c        = (const float*)d_in[25];
  const float* logT_c        = (const float*)d_in[26];
  const float* logT_t        = (const float*)d_in[27];
  const float* logT_id       = (const float*)d_in[28];
  float* out = (float*)d_out;

  float* p = (float*)d_ws;
  float* u_t   = p; p += (size_t)B_*HID_;
  float* u_i   = p; p += (size_t)B_*HID_;
  float* alp   = p; p += (size_t)B_*3;
  float* WihT  = p; p += 192*384;
  float* WhhT  = p; p += 128*384;
  float* Wt1uT = p; p += 256*128;
  float* Wt1sT = p; p += 128*128;
  float* Wi1uT = p; p += 192*128;
  float* Wi1sT = p; p += 64*128;
  float* Wa1T  = p; p += 128*64;

  k0_transpose<<<128, 256, 0, stream>>>(
      W_ih, W_hh, Wt1, Wi1, Wa1,
      WihT, WhhT, Wt1uT, Wt1sT, Wi1uT, Wi1sT, Wa1T);

  k1_gru<<<B_/TB, 256, 0, stream>>>(
      lengths, seq_id_emb, seq_text_emb,
      WihT, WhhT, b_ih, b_hh,
      Wt1uT, bt1, Wi1uT, bi1, Wa1T, ba1, Wa2, ba2,
      u_t, u_i, alp);

  k2_score<<<B_, 256, 0, stream>>>(
      seq_items, lengths, cand_ids,
      cand_id_emb, cand_text_emb, co_table,
      Wt1sT, Wt2, Wi1sT, Wi2,
      u_t, u_i, alp,
      beta_c, logT_c, logT_t, logT_id,
      out);
}